// Round 1
// baseline (763.481 us; speedup 1.0000x reference)
//
#include <hip/hip_runtime.h>
#include <stdint.h>

#define N_NODES 50000
#define N_EDGES 500000
#define NODE_IN 128
#define EDGE_IN 64
#define HID 128
#define K_H1 384   // 3*HID
#define N_H1 512   // 4*HID
#define N_H2 256   // 2*HID

typedef short s8v __attribute__((ext_vector_type(8)));   // 8 x bf16 bits (4 VGPR)
typedef float f4v __attribute__((ext_vector_type(4)));   // MFMA accumulator

__device__ __forceinline__ unsigned short bf16r(float f) {
    union { float f; unsigned int u; } v; v.f = f;
    unsigned int u = v.u + 0x7fffu + ((v.u >> 16) & 1u);  // round-nearest-even
    return (unsigned short)(u >> 16);
}

// Load 8 consecutive fp32 (two float4) from global, convert to bf16 A-fragment.
// A-frag layout for mfma_f32_16x16x32_bf16: lane holds A[m=lane&15][k=quad*8+j].
__device__ __forceinline__ s8v load_a_f32(const float* __restrict__ base, int row, int ld, int koff) {
    const float4* p = (const float4*)(base + row * ld + koff);
    float4 x0 = p[0];
    float4 x1 = p[1];
    union { s8v v; unsigned short s[8]; } r;
    r.s[0] = bf16r(x0.x); r.s[1] = bf16r(x0.y); r.s[2] = bf16r(x0.z); r.s[3] = bf16r(x0.w);
    r.s[4] = bf16r(x1.x); r.s[5] = bf16r(x1.y); r.s[6] = bf16r(x1.z); r.s[7] = bf16r(x1.w);
    return r.v;
}

// Pack B (KxN, row-major fp32) into fragment-ordered bf16:
// dst[(((kb*(N/16) + nt)*64 + lane)*8 + j] = B[kb*32 + (lane>>4)*8 + j][nt*16 + (lane&15)]
__global__ void pack_b(const float* __restrict__ src, unsigned short* __restrict__ dst, int K, int N) {
    int idx = blockIdx.x * blockDim.x + threadIdx.x;
    int total = K * N;
    if (idx >= total) return;
    int j = idx & 7;
    int lane = (idx >> 3) & 63;
    int rest = idx >> 9;
    int NT = N >> 4;
    int nt = rest % NT;
    int kb = rest / NT;
    int n = nt * 16 + (lane & 15);
    int k = kb * 32 + ((lane >> 4) << 3) + j;
    dst[idx] = bf16r(src[k * N + n]);
}

// node_f = relu(x @ Wn + bn) -> bf16 [N_NODES][HID]
// block: 256 threads (4 waves), 64 rows; wave w covers n-tiles {2w, 2w+1}
__global__ __launch_bounds__(256, 4) void node_feat_kernel(
    const float* __restrict__ x, const unsigned short* __restrict__ Wnp,
    const float* __restrict__ bn, unsigned short* __restrict__ node_f)
{
    int tid = threadIdx.x;
    int wave = tid >> 6, lane = tid & 63;
    int lm = lane & 15, quad = lane >> 4;
    int row0 = blockIdx.x * 64;

    f4v zero = {0.f, 0.f, 0.f, 0.f};
    f4v acc[4][2];
    for (int mt = 0; mt < 4; ++mt)
        for (int n = 0; n < 2; ++n) acc[mt][n] = zero;

    for (int kb = 0; kb < 4; ++kb) {
        s8v bfr[2];
        for (int n = 0; n < 2; ++n) {
            int ntg = wave * 2 + n;
            bfr[n] = *(const s8v*)(Wnp + (((kb * 8 + ntg) * 64 + lane) << 3));
        }
        for (int mt = 0; mt < 4; ++mt) {
            int row = row0 + mt * 16 + lm;
            if (row >= N_NODES) row = N_NODES - 1;
            s8v a = load_a_f32(x, row, NODE_IN, kb * 32 + quad * 8);
            for (int n = 0; n < 2; ++n)
                acc[mt][n] = __builtin_amdgcn_mfma_f32_16x16x32_bf16(a, bfr[n], acc[mt][n], 0, 0, 0);
        }
    }

    for (int n = 0; n < 2; ++n) {
        int col = (wave * 2 + n) * 16 + lm;
        float bv = bn[col];
        for (int mt = 0; mt < 4; ++mt) {
            for (int r = 0; r < 4; ++r) {
                int row = row0 + mt * 16 + quad * 4 + r;
                if (row < N_NODES) {
                    float v = fmaxf(acc[mt][n][r] + bv, 0.f);
                    node_f[row * HID + col] = bf16r(v);
                }
            }
        }
    }
}

// Fused per-edge pipeline: gather + edge_f + h1 + h2 + out
// block: 512 threads (8 waves), 128 edges.
#define CSTR 392   // comb row stride (elements, 384 + 8 pad)
#define H1STR 520  // h1 row stride (512 + 8 pad)

__global__ __launch_bounds__(512, 2) void fused_edge_kernel(
    const int* __restrict__ edge_index, const float* __restrict__ edge_attr,
    const unsigned short* __restrict__ node_f,
    const unsigned short* __restrict__ Wep, const float* __restrict__ be,
    const unsigned short* __restrict__ W1p, const float* __restrict__ b1,
    const unsigned short* __restrict__ W2p, const float* __restrict__ b2,
    const float* __restrict__ W3, const float* __restrict__ b3,
    float* __restrict__ out)
{
    // union buffer: phase1/2 comb [128][CSTR], phase3 h1 [128][H1STR] (133,120 B)
    __shared__ __align__(16) unsigned short smem[128 * H1STR];
    __shared__ float out_lds[128];

    int tid = threadIdx.x;
    int wave = tid >> 6, lane = tid & 63;
    int lm = lane & 15, quad = lane >> 4;
    int e0 = blockIdx.x * 128;

    if (tid < 128) out_lds[tid] = 0.f;

    // ---- Phase 1a: gather node_f[src], node_f[dst] into comb cols [0,256) ----
    {
        int i = tid >> 2, p = tid & 3;       // 4 threads per edge row, 32 cols each
        int e = e0 + i;
        int ec = e < N_EDGES ? e : N_EDGES - 1;
        int s = edge_index[ec];
        int d = edge_index[N_EDGES + ec];
        const uint4* ps = (const uint4*)(node_f + s * HID + p * 32);
        const uint4* pd = (const uint4*)(node_f + d * HID + p * 32);
        uint4* cs = (uint4*)(smem + i * CSTR + p * 32);
        uint4* cd = (uint4*)(smem + i * CSTR + 128 + p * 32);
        #pragma unroll
        for (int c = 0; c < 4; ++c) cs[c] = ps[c];
        #pragma unroll
        for (int c = 0; c < 4; ++c) cd[c] = pd[c];
    }

    // ---- Phase 1b: edge_f = relu(edge_attr @ We + be) into comb cols [256,384) ----
    {
        f4v zero = {0.f, 0.f, 0.f, 0.f};
        f4v acc[8];
        #pragma unroll
        for (int mt = 0; mt < 8; ++mt) acc[mt] = zero;
        int nt = wave;  // 8 waves cover 8 n-tiles of HID=128
        for (int kb = 0; kb < 2; ++kb) {
            s8v b = *(const s8v*)(Wep + (((kb * 8 + nt) * 64 + lane) << 3));
            #pragma unroll
            for (int mt = 0; mt < 8; ++mt) {
                int row = e0 + mt * 16 + lm;
                if (row >= N_EDGES) row = N_EDGES - 1;
                s8v a = load_a_f32(edge_attr, row, EDGE_IN, kb * 32 + quad * 8);
                acc[mt] = __builtin_amdgcn_mfma_f32_16x16x32_bf16(a, b, acc[mt], 0, 0, 0);
            }
        }
        int col = nt * 16 + lm;
        float bv = be[col];
        #pragma unroll
        for (int mt = 0; mt < 8; ++mt)
            #pragma unroll
            for (int r = 0; r < 4; ++r) {
                float v = fmaxf(acc[mt][r] + bv, 0.f);
                smem[(mt * 16 + quad * 4 + r) * CSTR + 256 + col] = bf16r(v);
            }
    }
    __syncthreads();

    // ---- Phase 2: h1 = relu(comb @ W1 + b1), acc in registers ----
    f4v zero = {0.f, 0.f, 0.f, 0.f};
    f4v acc1[8][4];
    #pragma unroll
    for (int mt = 0; mt < 8; ++mt)
        #pragma unroll
        for (int n = 0; n < 4; ++n) acc1[mt][n] = zero;

    for (int kb = 0; kb < 12; ++kb) {
        s8v bfr[4];
        #pragma unroll
        for (int n = 0; n < 4; ++n) {
            int ntg = wave * 4 + n;   // 8 waves x 4 tiles = 32 n-tiles = 512 cols
            bfr[n] = *(const s8v*)(W1p + (((kb * 32 + ntg) * 64 + lane) << 3));
        }
        #pragma unroll
        for (int mt = 0; mt < 8; ++mt) {
            s8v a = *(const s8v*)(smem + (mt * 16 + lm) * CSTR + kb * 32 + quad * 8);
            #pragma unroll
            for (int n = 0; n < 4; ++n)
                acc1[mt][n] = __builtin_amdgcn_mfma_f32_16x16x32_bf16(a, bfr[n], acc1[mt][n], 0, 0, 0);
        }
    }
    __syncthreads();  // everyone done reading comb before we overwrite with h1

    #pragma unroll
    for (int n = 0; n < 4; ++n) {
        int col = (wave * 4 + n) * 16 + lm;
        float bv = b1[col];
        #pragma unroll
        for (int mt = 0; mt < 8; ++mt)
            #pragma unroll
            for (int r = 0; r < 4; ++r) {
                float v = fmaxf(acc1[mt][n][r] + bv, 0.f);
                smem[(mt * 16 + quad * 4 + r) * H1STR + col] = bf16r(v);
            }
    }
    __syncthreads();

    // ---- Phase 3: h2 = relu(h1 @ W2 + b2); W3-dot fused into epilogue (fp32) ----
    f4v acc2[8][2];
    #pragma unroll
    for (int mt = 0; mt < 8; ++mt)
        #pragma unroll
        for (int n = 0; n < 2; ++n) acc2[mt][n] = zero;

    for (int kb = 0; kb < 16; ++kb) {
        s8v bfr[2];
        #pragma unroll
        for (int n = 0; n < 2; ++n) {
            int ntg = wave * 2 + n;   // 8 waves x 2 tiles = 16 n-tiles = 256 cols
            bfr[n] = *(const s8v*)(W2p + (((kb * 16 + ntg) * 64 + lane) << 3));
        }
        #pragma unroll
        for (int mt = 0; mt < 8; ++mt) {
            s8v a = *(const s8v*)(smem + (mt * 16 + lm) * H1STR + kb * 32 + quad * 8);
            #pragma unroll
            for (int n = 0; n < 2; ++n)
                acc2[mt][n] = __builtin_amdgcn_mfma_f32_16x16x32_bf16(a, bfr[n], acc2[mt][n], 0, 0, 0);
        }
    }

    float b2v[2], w3v[2];
    #pragma unroll
    for (int n = 0; n < 2; ++n) {
        int col = (wave * 2 + n) * 16 + lm;
        b2v[n] = b2[col];
        w3v[n] = W3[col];
    }
    #pragma unroll
    for (int mt = 0; mt < 8; ++mt) {
        #pragma unroll
        for (int r = 0; r < 4; ++r) {
            float p = 0.f;
            #pragma unroll
            for (int n = 0; n < 2; ++n)
                p += fmaxf(acc2[mt][n][r] + b2v[n], 0.f) * w3v[n];
            // reduce the 16 lanes of this quad (they hold 16 different cols, same row)
            p += __shfl_xor(p, 1, 16);
            p += __shfl_xor(p, 2, 16);
            p += __shfl_xor(p, 4, 16);
            p += __shfl_xor(p, 8, 16);
            if (lm == 0)
                atomicAdd(&out_lds[mt * 16 + quad * 4 + r], p);
        }
    }
    __syncthreads();

    if (tid < 128) {
        int e = e0 + tid;
        if (e < N_EDGES) out[e] = out_lds[tid] + b3[0];
    }
}

extern "C" void kernel_launch(void* const* d_in, const int* in_sizes, int n_in,
                              void* d_out, int out_size, void* d_ws, size_t ws_size,
                              hipStream_t stream)
{
    const float* x          = (const float*)d_in[0];
    const int*   edge_index = (const int*)d_in[1];
    const float* edge_attr  = (const float*)d_in[2];
    const float* Wn = (const float*)d_in[3];
    const float* bn = (const float*)d_in[4];
    const float* We = (const float*)d_in[5];
    const float* be = (const float*)d_in[6];
    const float* W1 = (const float*)d_in[7];
    const float* b1 = (const float*)d_in[8];
    const float* W2 = (const float*)d_in[9];
    const float* b2 = (const float*)d_in[10];
    const float* W3 = (const float*)d_in[11];
    const float* b3 = (const float*)d_in[12];
    float* out = (float*)d_out;

    char* ws = (char*)d_ws;
    unsigned short* node_f = (unsigned short*)ws;                    // 12,800,000 B
    unsigned short* Wnp = (unsigned short*)(ws + 12800000);          // 32,768 B
    unsigned short* Wep = (unsigned short*)(ws + 12832768);          // 16,384 B
    unsigned short* W1p = (unsigned short*)(ws + 12849152);          // 393,216 B
    unsigned short* W2p = (unsigned short*)(ws + 13242368);          // 262,144 B

    pack_b<<<(NODE_IN * HID + 255) / 256, 256, 0, stream>>>(Wn, Wnp, NODE_IN, HID);
    pack_b<<<(EDGE_IN * HID + 255) / 256, 256, 0, stream>>>(We, Wep, EDGE_IN, HID);
    pack_b<<<(K_H1 * N_H1 + 255) / 256, 256, 0, stream>>>(W1, W1p, K_H1, N_H1);
    pack_b<<<(N_H1 * N_H2 + 255) / 256, 256, 0, stream>>>(W2, W2p, N_H1, N_H2);

    node_feat_kernel<<<(N_NODES + 63) / 64, 256, 0, stream>>>(x, Wnp, bn, node_f);

    fused_edge_kernel<<<(N_EDGES + 127) / 128, 512, 0, stream>>>(
        edge_index, edge_attr, node_f, Wep, be, W1p, b1, W2p, b2, W3, b3, out);
}

// Round 2
// 636.166 us; speedup vs baseline: 1.2001x; 1.2001x over previous
//
#include <hip/hip_runtime.h>
#include <stdint.h>

#define N_NODES 50000
#define N_EDGES 500000
#define NODE_IN 128
#define EDGE_IN 64
#define HID 128
#define K_H1 384   // 3*HID
#define N_H1 512   // 4*HID
#define N_H2 256   // 2*HID

#define EPB 64     // edges per block (halved from 128 -> 2 blocks/CU)

typedef short s8v __attribute__((ext_vector_type(8)));   // 8 x bf16 bits (4 VGPR)
typedef float f4v __attribute__((ext_vector_type(4)));   // MFMA accumulator

__device__ __forceinline__ unsigned short bf16r(float f) {
    union { float f; unsigned int u; } v; v.f = f;
    unsigned int u = v.u + 0x7fffu + ((v.u >> 16) & 1u);  // round-nearest-even
    return (unsigned short)(u >> 16);
}

// Load 8 consecutive fp32 (two float4) from global, convert to bf16 A-fragment.
// A-frag layout for mfma_f32_16x16x32_bf16: lane holds A[m=lane&15][k=quad*8+j].
__device__ __forceinline__ s8v load_a_f32(const float* __restrict__ base, int row, int ld, int koff) {
    const float4* p = (const float4*)(base + row * ld + koff);
    float4 x0 = p[0];
    float4 x1 = p[1];
    union { s8v v; unsigned short s[8]; } r;
    r.s[0] = bf16r(x0.x); r.s[1] = bf16r(x0.y); r.s[2] = bf16r(x0.z); r.s[3] = bf16r(x0.w);
    r.s[4] = bf16r(x1.x); r.s[5] = bf16r(x1.y); r.s[6] = bf16r(x1.z); r.s[7] = bf16r(x1.w);
    return r.v;
}

// Pack B (KxN, row-major fp32) into fragment-ordered bf16:
// dst[(((kb*(N/16) + nt)*64 + lane)*8 + j] = B[kb*32 + (lane>>4)*8 + j][nt*16 + (lane&15)]
__global__ void pack_b(const float* __restrict__ src, unsigned short* __restrict__ dst, int K, int N) {
    int idx = blockIdx.x * blockDim.x + threadIdx.x;
    int total = K * N;
    if (idx >= total) return;
    int j = idx & 7;
    int lane = (idx >> 3) & 63;
    int rest = idx >> 9;
    int NT = N >> 4;
    int nt = rest % NT;
    int kb = rest / NT;
    int n = nt * 16 + (lane & 15);
    int k = kb * 32 + ((lane >> 4) << 3) + j;
    dst[idx] = bf16r(src[k * N + n]);
}

// node_f = relu(x @ Wn + bn) -> bf16 [N_NODES][HID]
// block: 256 threads (4 waves), 64 rows; wave w covers n-tiles {2w, 2w+1}
__global__ __launch_bounds__(256, 4) void node_feat_kernel(
    const float* __restrict__ x, const unsigned short* __restrict__ Wnp,
    const float* __restrict__ bn, unsigned short* __restrict__ node_f)
{
    int tid = threadIdx.x;
    int wave = tid >> 6, lane = tid & 63;
    int lm = lane & 15, quad = lane >> 4;
    int row0 = blockIdx.x * 64;

    f4v zero = {0.f, 0.f, 0.f, 0.f};
    f4v acc[4][2];
    for (int mt = 0; mt < 4; ++mt)
        for (int n = 0; n < 2; ++n) acc[mt][n] = zero;

    for (int kb = 0; kb < 4; ++kb) {
        s8v bfr[2];
        for (int n = 0; n < 2; ++n) {
            int ntg = wave * 2 + n;
            bfr[n] = *(const s8v*)(Wnp + (((kb * 8 + ntg) * 64 + lane) << 3));
        }
        for (int mt = 0; mt < 4; ++mt) {
            int row = row0 + mt * 16 + lm;
            if (row >= N_NODES) row = N_NODES - 1;
            s8v a = load_a_f32(x, row, NODE_IN, kb * 32 + quad * 8);
            for (int n = 0; n < 2; ++n)
                acc[mt][n] = __builtin_amdgcn_mfma_f32_16x16x32_bf16(a, bfr[n], acc[mt][n], 0, 0, 0);
        }
    }

    for (int n = 0; n < 2; ++n) {
        int col = (wave * 2 + n) * 16 + lm;
        float bv = bn[col];
        for (int mt = 0; mt < 4; ++mt) {
            for (int r = 0; r < 4; ++r) {
                int row = row0 + mt * 16 + quad * 4 + r;
                if (row < N_NODES) {
                    float v = fmaxf(acc[mt][n][r] + bv, 0.f);
                    node_f[row * HID + col] = bf16r(v);
                }
            }
        }
    }
}

// Fused per-edge pipeline: gather + edge_f + h1 + h2 + out
// block: 512 threads (8 waves), 64 edges. LDS ~66.8 KB -> 2 blocks/CU.
#define CSTR 392   // comb row stride (elements, 384 + 8 pad)
#define H1STR 520  // h1 row stride (512 + 8 pad)

__global__ __launch_bounds__(512, 4) void fused_edge_kernel(
    const int* __restrict__ edge_index, const float* __restrict__ edge_attr,
    const unsigned short* __restrict__ node_f,
    const unsigned short* __restrict__ Wep, const float* __restrict__ be,
    const unsigned short* __restrict__ W1p, const float* __restrict__ b1,
    const unsigned short* __restrict__ W2p, const float* __restrict__ b2,
    const float* __restrict__ W3, const float* __restrict__ b3,
    float* __restrict__ out)
{
    // union buffer: phase1/2 comb [EPB][CSTR], phase3 h1 [EPB][H1STR] (66,560 B)
    __shared__ __align__(16) unsigned short smem[EPB * H1STR];
    __shared__ float out_lds[EPB];

    int tid = threadIdx.x;
    int wave = tid >> 6, lane = tid & 63;
    int lm = lane & 15, quad = lane >> 4;
    int e0 = blockIdx.x * EPB;

    if (tid < EPB) out_lds[tid] = 0.f;

    // ---- Phase 1a: gather node_f[src], node_f[dst] into comb cols [0,256) ----
    {
        int i = tid >> 3, p = tid & 7;       // 8 threads per edge row, 16 cols (32 B) each
        int e = e0 + i;
        int ec = e < N_EDGES ? e : N_EDGES - 1;
        int s = edge_index[ec];
        int d = edge_index[N_EDGES + ec];
        const uint4* ps = (const uint4*)(node_f + s * HID + p * 16);
        const uint4* pd = (const uint4*)(node_f + d * HID + p * 16);
        uint4* cs = (uint4*)(smem + i * CSTR + p * 16);
        uint4* cd = (uint4*)(smem + i * CSTR + 128 + p * 16);
        cs[0] = ps[0]; cs[1] = ps[1];
        cd[0] = pd[0]; cd[1] = pd[1];
    }

    // ---- Phase 1b: edge_f = relu(edge_attr @ We + be) into comb cols [256,384) ----
    {
        f4v zero = {0.f, 0.f, 0.f, 0.f};
        f4v acc[4];
        #pragma unroll
        for (int mt = 0; mt < 4; ++mt) acc[mt] = zero;
        int nt = wave;  // 8 waves cover 8 n-tiles of HID=128
        for (int kb = 0; kb < 2; ++kb) {
            s8v b = *(const s8v*)(Wep + (((kb * 8 + nt) * 64 + lane) << 3));
            #pragma unroll
            for (int mt = 0; mt < 4; ++mt) {
                int row = e0 + mt * 16 + lm;
                if (row >= N_EDGES) row = N_EDGES - 1;
                s8v a = load_a_f32(edge_attr, row, EDGE_IN, kb * 32 + quad * 8);
                acc[mt] = __builtin_amdgcn_mfma_f32_16x16x32_bf16(a, b, acc[mt], 0, 0, 0);
            }
        }
        int col = nt * 16 + lm;
        float bv = be[col];
        #pragma unroll
        for (int mt = 0; mt < 4; ++mt)
            #pragma unroll
            for (int r = 0; r < 4; ++r) {
                float v = fmaxf(acc[mt][r] + bv, 0.f);
                smem[(mt * 16 + quad * 4 + r) * CSTR + 256 + col] = bf16r(v);
            }
    }
    __syncthreads();

    // ---- Phase 2: h1 = relu(comb @ W1 + b1), acc in registers ----
    f4v zero = {0.f, 0.f, 0.f, 0.f};
    f4v acc1[4][4];
    #pragma unroll
    for (int mt = 0; mt < 4; ++mt)
        #pragma unroll
        for (int n = 0; n < 4; ++n) acc1[mt][n] = zero;

    for (int kb = 0; kb < 12; ++kb) {
        s8v bfr[4];
        #pragma unroll
        for (int n = 0; n < 4; ++n) {
            int ntg = wave * 4 + n;   // 8 waves x 4 tiles = 32 n-tiles = 512 cols
            bfr[n] = *(const s8v*)(W1p + (((kb * 32 + ntg) * 64 + lane) << 3));
        }
        #pragma unroll
        for (int mt = 0; mt < 4; ++mt) {
            s8v a = *(const s8v*)(smem + (mt * 16 + lm) * CSTR + kb * 32 + quad * 8);
            #pragma unroll
            for (int n = 0; n < 4; ++n)
                acc1[mt][n] = __builtin_amdgcn_mfma_f32_16x16x32_bf16(a, bfr[n], acc1[mt][n], 0, 0, 0);
        }
    }
    __syncthreads();  // everyone done reading comb before we overwrite with h1

    #pragma unroll
    for (int n = 0; n < 4; ++n) {
        int col = (wave * 4 + n) * 16 + lm;
        float bv = b1[col];
        #pragma unroll
        for (int mt = 0; mt < 4; ++mt)
            #pragma unroll
            for (int r = 0; r < 4; ++r) {
                float v = fmaxf(acc1[mt][n][r] + bv, 0.f);
                smem[(mt * 16 + quad * 4 + r) * H1STR + col] = bf16r(v);
            }
    }
    __syncthreads();

    // ---- Phase 3: h2 = relu(h1 @ W2 + b2); W3-dot fused into epilogue (fp32) ----
    f4v acc2[4][2];
    #pragma unroll
    for (int mt = 0; mt < 4; ++mt)
        #pragma unroll
        for (int n = 0; n < 2; ++n) acc2[mt][n] = zero;

    for (int kb = 0; kb < 16; ++kb) {
        s8v bfr[2];
        #pragma unroll
        for (int n = 0; n < 2; ++n) {
            int ntg = wave * 2 + n;   // 8 waves x 2 tiles = 16 n-tiles = 256 cols
            bfr[n] = *(const s8v*)(W2p + (((kb * 16 + ntg) * 64 + lane) << 3));
        }
        #pragma unroll
        for (int mt = 0; mt < 4; ++mt) {
            s8v a = *(const s8v*)(smem + (mt * 16 + lm) * H1STR + kb * 32 + quad * 8);
            #pragma unroll
            for (int n = 0; n < 2; ++n)
                acc2[mt][n] = __builtin_amdgcn_mfma_f32_16x16x32_bf16(a, bfr[n], acc2[mt][n], 0, 0, 0);
        }
    }

    float b2v[2], w3v[2];
    #pragma unroll
    for (int n = 0; n < 2; ++n) {
        int col = (wave * 2 + n) * 16 + lm;
        b2v[n] = b2[col];
        w3v[n] = W3[col];
    }
    #pragma unroll
    for (int mt = 0; mt < 4; ++mt) {
        #pragma unroll
        for (int r = 0; r < 4; ++r) {
            float p = 0.f;
            #pragma unroll
            for (int n = 0; n < 2; ++n)
                p += fmaxf(acc2[mt][n][r] + b2v[n], 0.f) * w3v[n];
            // reduce the 16 lanes of this quad (they hold 16 different cols, same row)
            p += __shfl_xor(p, 1, 16);
            p += __shfl_xor(p, 2, 16);
            p += __shfl_xor(p, 4, 16);
            p += __shfl_xor(p, 8, 16);
            if (lm == 0)
                atomicAdd(&out_lds[mt * 16 + quad * 4 + r], p);
        }
    }
    __syncthreads();

    if (tid < EPB) {
        int e = e0 + tid;
        if (e < N_EDGES) out[e] = out_lds[tid] + b3[0];
    }
}

extern "C" void kernel_launch(void* const* d_in, const int* in_sizes, int n_in,
                              void* d_out, int out_size, void* d_ws, size_t ws_size,
                              hipStream_t stream)
{
    const float* x          = (const float*)d_in[0];
    const int*   edge_index = (const int*)d_in[1];
    const float* edge_attr  = (const float*)d_in[2];
    const float* Wn = (const float*)d_in[3];
    const float* bn = (const float*)d_in[4];
    const float* We = (const float*)d_in[5];
    const float* be = (const float*)d_in[6];
    const float* W1 = (const float*)d_in[7];
    const float* b1 = (const float*)d_in[8];
    const float* W2 = (const float*)d_in[9];
    const float* b2 = (const float*)d_in[10];
    const float* W3 = (const float*)d_in[11];
    const float* b3 = (const float*)d_in[12];
    float* out = (float*)d_out;

    char* ws = (char*)d_ws;
    unsigned short* node_f = (unsigned short*)ws;                    // 12,800,000 B
    unsigned short* Wnp = (unsigned short*)(ws + 12800000);          // 32,768 B
    unsigned short* Wep = (unsigned short*)(ws + 12832768);          // 16,384 B
    unsigned short* W1p = (unsigned short*)(ws + 12849152);          // 393,216 B
    unsigned short* W2p = (unsigned short*)(ws + 13242368);          // 262,144 B

    pack_b<<<(NODE_IN * HID + 255) / 256, 256, 0, stream>>>(Wn, Wnp, NODE_IN, HID);
    pack_b<<<(EDGE_IN * HID + 255) / 256, 256, 0, stream>>>(We, Wep, EDGE_IN, HID);
    pack_b<<<(K_H1 * N_H1 + 255) / 256, 256, 0, stream>>>(W1, W1p, K_H1, N_H1);
    pack_b<<<(N_H1 * N_H2 + 255) / 256, 256, 0, stream>>>(W2, W2p, N_H1, N_H2);

    node_feat_kernel<<<(N_NODES + 63) / 64, 256, 0, stream>>>(x, Wnp, bn, node_f);

    fused_edge_kernel<<<(N_EDGES + EPB - 1) / EPB, 512, 0, stream>>>(
        edge_index, edge_attr, node_f, Wep, be, W1p, b1, W2p, b2, W3, b3, out);
}

// Round 4
// 572.981 us; speedup vs baseline: 1.3325x; 1.1103x over previous
//
#include <hip/hip_runtime.h>
#include <hip/hip_bf16.h>
#include <stdint.h>

#define N_NODES 50000
#define N_EDGES 500000
#define NODE_IN 128
#define EDGE_IN 64
#define HID 128
#define K_H1 384   // 3*HID
#define N_H1 512   // 4*HID
#define N_H2 256   // 2*HID

#define EPB 64     // edges per block -> 2 blocks/CU

typedef short s8v __attribute__((ext_vector_type(8)));   // 8 x bf16 bits (4 VGPR)
typedef float f4v __attribute__((ext_vector_type(4)));   // MFMA accumulator

// HW packed fp32->bf16 (v_cvt_pk_bf16_f32): low 16 bits = a, high = b
__device__ __forceinline__ unsigned int pk_bf16(float a, float b) {
    union { __hip_bfloat162 h; unsigned int u; } c;
    c.h = __float22bfloat162_rn(float2{a, b});
    return c.u;
}

// Load 8 consecutive fp32 from global, convert to a bf16 fragment.
// Fragment map (A and B identical): lane(lm,quad) holds [other=lm][k=quad*8+j].
__device__ __forceinline__ s8v load_a_f32(const float* __restrict__ base, int row, int ld, int koff) {
    const float4* p = (const float4*)(base + row * ld + koff);
    float4 x0 = p[0];
    float4 x1 = p[1];
    union { s8v v; unsigned int u[4]; } r;
    r.u[0] = pk_bf16(x0.x, x0.y);
    r.u[1] = pk_bf16(x0.z, x0.w);
    r.u[2] = pk_bf16(x1.x, x1.y);
    r.u[3] = pk_bf16(x1.z, x1.w);
    return r.v;
}

// Pack W (KxN row-major fp32) into fragment-ordered bf16:
// dst[(((kb*(N/16) + nt)*64 + lane)*8 + j] = W[kb*32 + (lane>>4)*8 + j][nt*16 + (lane&15)]
// Serves as B-frag for D=X@W, and as A-frag (=W^T) for the swapped D=W^T@X^T.
__device__ __forceinline__ void pack_one(const float* __restrict__ src, unsigned short* __restrict__ dst,
                                         int idx, int N) {
    int j = idx & 7;
    int lane = (idx >> 3) & 63;
    int rest = idx >> 9;
    int NT = N >> 4;
    int nt = rest % NT;
    int kb = rest / NT;
    int n = nt * 16 + (lane & 15);
    int k = kb * 32 + ((lane >> 4) << 3) + j;
    union { __hip_bfloat16 h; unsigned short s; } c;
    c.h = __float2bfloat16(src[k * N + n]);
    dst[idx] = c.s;
}

#define WN_ELEMS (NODE_IN * HID)          // 16384
#define WE_ELEMS (EDGE_IN * HID)          // 8192
#define W1_ELEMS (K_H1 * N_H1)            // 196608
#define W2_ELEMS (N_H1 * N_H2)            // 131072
#define PACK_TOTAL (WN_ELEMS + WE_ELEMS + W1_ELEMS + W2_ELEMS)

__global__ void pack_all(const float* __restrict__ Wn, const float* __restrict__ We,
                         const float* __restrict__ W1, const float* __restrict__ W2,
                         unsigned short* __restrict__ Wnp, unsigned short* __restrict__ Wep,
                         unsigned short* __restrict__ W1p, unsigned short* __restrict__ W2p) {
    int idx = blockIdx.x * blockDim.x + threadIdx.x;
    if (idx >= PACK_TOTAL) return;
    if (idx < WN_ELEMS) { pack_one(Wn, Wnp, idx, HID); return; }
    idx -= WN_ELEMS;
    if (idx < WE_ELEMS) { pack_one(We, Wep, idx, HID); return; }
    idx -= WE_ELEMS;
    if (idx < W1_ELEMS) { pack_one(W1, W1p, idx, N_H1); return; }
    idx -= W1_ELEMS;
    pack_one(W2, W2p, idx, N_H2);
}

// node_f^T formulation: D[m=hidcol][n=node] = Wn^T @ x^T.
// block: 256 threads (4 waves), 64 nodes; wave w owns node-tile nt=w, all 8 m-tiles.
__global__ __launch_bounds__(256, 4) void node_feat_kernel(
    const float* __restrict__ x, const unsigned short* __restrict__ Wnp,
    const float* __restrict__ bn, unsigned short* __restrict__ node_f)
{
    int tid = threadIdx.x;
    int wave = tid >> 6, lane = tid & 63;
    int lm = lane & 15, quad = lane >> 4;
    int row0 = blockIdx.x * 64;
    int node = row0 + wave * 16 + lm;
    int nodec = node < N_NODES ? node : N_NODES - 1;

    f4v zero = {0.f, 0.f, 0.f, 0.f};
    f4v acc[8];
    #pragma unroll
    for (int mt = 0; mt < 8; ++mt) acc[mt] = zero;

    for (int kb = 0; kb < 4; ++kb) {
        s8v b = load_a_f32(x, nodec, NODE_IN, kb * 32 + quad * 8);
        #pragma unroll
        for (int mt = 0; mt < 8; ++mt) {
            s8v a = *(const s8v*)(Wnp + (((kb * 8 + mt) * 64 + lane) << 3));
            acc[mt] = __builtin_amdgcn_mfma_f32_16x16x32_bf16(a, b, acc[mt], 0, 0, 0);
        }
    }

    if (node < N_NODES) {
        #pragma unroll
        for (int mt = 0; mt < 8; ++mt) {
            float4 bv = *(const float4*)(bn + mt * 16 + quad * 4);
            uint2 pk;
            pk.x = pk_bf16(fmaxf(acc[mt][0] + bv.x, 0.f), fmaxf(acc[mt][1] + bv.y, 0.f));
            pk.y = pk_bf16(fmaxf(acc[mt][2] + bv.z, 0.f), fmaxf(acc[mt][3] + bv.w, 0.f));
            *(uint2*)(node_f + node * HID + mt * 16 + quad * 4) = pk;
        }
    }
}

// Fused per-edge pipeline (all GEMMs in swapped D=W^T@X^T form).
// block: 512 threads (8 waves), 64 edges. LDS ~66.8 KB -> 2 blocks/CU.
#define CSTR 392   // comb row stride (shorts, 384 + 8 pad)
#define H1STR 520  // h1 row stride (shorts, 512 + 8 pad)

__global__ __launch_bounds__(512, 4) void fused_edge_kernel(
    const int* __restrict__ edge_index, const float* __restrict__ edge_attr,
    const unsigned short* __restrict__ node_f,
    const unsigned short* __restrict__ Wep, const float* __restrict__ be,
    const unsigned short* __restrict__ W1p, const float* __restrict__ b1,
    const unsigned short* __restrict__ W2p, const float* __restrict__ b2,
    const float* __restrict__ W3, const float* __restrict__ b3,
    float* __restrict__ out)
{
    // union buffer: phase1/2 comb [EPB][CSTR] (row-major), phase3 h1 [EPB][H1STR]
    __shared__ __align__(16) unsigned short smem[EPB * H1STR];
    __shared__ float out_lds[EPB];

    int tid = threadIdx.x;
    int wave = tid >> 6, lane = tid & 63;
    int lm = lane & 15, quad = lane >> 4;
    int e0 = blockIdx.x * EPB;

    if (tid < EPB) out_lds[tid] = 0.f;

    // ---- Phase 1a (issue): gather loads of node_f[src], node_f[dst] into regs ----
    // 8 threads per edge row; each thread owns a 16-short (32 B) chunk of src AND dst.
    int gi = tid >> 3, gp = tid & 7;
    uint4 gs0, gs1, gd0, gd1;
    {
        int e = e0 + gi;
        int ec = e < N_EDGES ? e : N_EDGES - 1;
        int s = edge_index[ec];
        int d = edge_index[N_EDGES + ec];
        const uint4* ps = (const uint4*)(node_f + s * HID + gp * 16);
        const uint4* pd = (const uint4*)(node_f + d * HID + gp * 16);
        gs0 = ps[0]; gs1 = ps[1];
        gd0 = pd[0]; gd1 = pd[1];
    }

    // ---- Phase 1b: edge_f^T = We^T @ edge_attr^T, cols [256,384) of comb ----
    // wave w: edge-tile nt = w%4, m-tiles mtg = (w/4)*4 + t (t=0..3)
    {
        int nt = wave & 3;
        int mbase = (wave >> 2) * 4;
        int erow = e0 + nt * 16 + lm;
        if (erow >= N_EDGES) erow = N_EDGES - 1;

        f4v zero = {0.f, 0.f, 0.f, 0.f};
        f4v acc[4];
        #pragma unroll
        for (int t = 0; t < 4; ++t) acc[t] = zero;

        for (int kb = 0; kb < 2; ++kb) {
            s8v b = load_a_f32(edge_attr, erow, EDGE_IN, kb * 32 + quad * 8);
            #pragma unroll
            for (int t = 0; t < 4; ++t) {
                s8v a = *(const s8v*)(Wep + (((kb * 8 + mbase + t) * 64 + lane) << 3));
                acc[t] = __builtin_amdgcn_mfma_f32_16x16x32_bf16(a, b, acc[t], 0, 0, 0);
            }
        }
        // write gather results (loads have had phase1b to complete)
        {
            uint4* cs = (uint4*)(smem + gi * CSTR + gp * 16);
            uint4* cd = (uint4*)(smem + gi * CSTR + 128 + gp * 16);
            cs[0] = gs0; cs[1] = gs1;
            cd[0] = gd0; cd[1] = gd1;
        }
        // edge_f epilogue: b64 writes, 4 consecutive cols per lane
        int edge = nt * 16 + lm;
        #pragma unroll
        for (int t = 0; t < 4; ++t) {
            int col = (mbase + t) * 16 + quad * 4;
            float4 bv = *(const float4*)(be + col);
            uint2 pk;
            pk.x = pk_bf16(fmaxf(acc[t][0] + bv.x, 0.f), fmaxf(acc[t][1] + bv.y, 0.f));
            pk.y = pk_bf16(fmaxf(acc[t][2] + bv.z, 0.f), fmaxf(acc[t][3] + bv.w, 0.f));
            *(uint2*)(smem + edge * CSTR + 256 + col) = pk;
        }
    }
    __syncthreads();

    // ---- Phase 2: h1^T = W1^T @ comb^T; wave w owns m-tiles mtg = w*4+t, all 4 edge-tiles ----
    f4v zero = {0.f, 0.f, 0.f, 0.f};
    f4v acc1[4][4];
    #pragma unroll
    for (int t = 0; t < 4; ++t)
        #pragma unroll
        for (int nt = 0; nt < 4; ++nt) acc1[t][nt] = zero;

    {
        s8v afr[4];
        #pragma unroll
        for (int t = 0; t < 4; ++t)
            afr[t] = *(const s8v*)(W1p + (((0 * 32 + wave * 4 + t) * 64 + lane) << 3));
        for (int kb = 0; kb < 12; ++kb) {
            s8v bfr[4];
            #pragma unroll
            for (int nt = 0; nt < 4; ++nt)
                bfr[nt] = *(const s8v*)(smem + (nt * 16 + lm) * CSTR + kb * 32 + quad * 8);
            int kbn = kb < 11 ? kb + 1 : 11;
            s8v anx[4];
            #pragma unroll
            for (int t = 0; t < 4; ++t)
                anx[t] = *(const s8v*)(W1p + (((kbn * 32 + wave * 4 + t) * 64 + lane) << 3));
            #pragma unroll
            for (int t = 0; t < 4; ++t)
                #pragma unroll
                for (int nt = 0; nt < 4; ++nt)
                    acc1[t][nt] = __builtin_amdgcn_mfma_f32_16x16x32_bf16(afr[t], bfr[nt], acc1[t][nt], 0, 0, 0);
            #pragma unroll
            for (int t = 0; t < 4; ++t) afr[t] = anx[t];
        }
    }
    __syncthreads();  // everyone done reading comb before h1 overwrites it

    #pragma unroll
    for (int t = 0; t < 4; ++t) {
        int col = (wave * 4 + t) * 16 + quad * 4;
        float4 bv = *(const float4*)(b1 + col);
        #pragma unroll
        for (int nt = 0; nt < 4; ++nt) {
            int edge = nt * 16 + lm;
            uint2 pk;
            pk.x = pk_bf16(fmaxf(acc1[t][nt][0] + bv.x, 0.f), fmaxf(acc1[t][nt][1] + bv.y, 0.f));
            pk.y = pk_bf16(fmaxf(acc1[t][nt][2] + bv.z, 0.f), fmaxf(acc1[t][nt][3] + bv.w, 0.f));
            *(uint2*)(smem + edge * H1STR + col) = pk;
        }
    }
    __syncthreads();

    // ---- Phase 3: h2^T = W2^T @ h1^T; wave w owns m-tiles mtg = w*2+t, all 4 edge-tiles ----
    f4v acc2[2][4];
    #pragma unroll
    for (int t = 0; t < 2; ++t)
        #pragma unroll
        for (int nt = 0; nt < 4; ++nt) acc2[t][nt] = zero;

    {
        s8v afr[2];
        #pragma unroll
        for (int t = 0; t < 2; ++t)
            afr[t] = *(const s8v*)(W2p + (((0 * 16 + wave * 2 + t) * 64 + lane) << 3));
        for (int kb = 0; kb < 16; ++kb) {
            s8v bfr[4];
            #pragma unroll
            for (int nt = 0; nt < 4; ++nt)
                bfr[nt] = *(const s8v*)(smem + (nt * 16 + lm) * H1STR + kb * 32 + quad * 8);
            int kbn = kb < 15 ? kb + 1 : 15;
            s8v anx[2];
            #pragma unroll
            for (int t = 0; t < 2; ++t)
                anx[t] = *(const s8v*)(W2p + (((kbn * 16 + wave * 2 + t) * 64 + lane) << 3));
            #pragma unroll
            for (int t = 0; t < 2; ++t)
                #pragma unroll
                for (int nt = 0; nt < 4; ++nt)
                    acc2[t][nt] = __builtin_amdgcn_mfma_f32_16x16x32_bf16(afr[t], bfr[nt], acc2[t][nt], 0, 0, 0);
            #pragma unroll
            for (int t = 0; t < 2; ++t) afr[t] = anx[t];
        }
    }

    // ---- Epilogue: relu(h2+b2) . W3 — per-lane partial over 8 h2-cols, quad-reduce ----
    {
        float4 b2v[2], w3v[2];
        #pragma unroll
        for (int t = 0; t < 2; ++t) {
            int col = (wave * 2 + t) * 16 + quad * 4;
            b2v[t] = *(const float4*)(b2 + col);
            w3v[t] = *(const float4*)(W3 + col);
        }
        #pragma unroll
        for (int nt = 0; nt < 4; ++nt) {
            float p = 0.f;
            #pragma unroll
            for (int t = 0; t < 2; ++t) {
                p += fmaxf(acc2[t][nt][0] + b2v[t].x, 0.f) * w3v[t].x;
                p += fmaxf(acc2[t][nt][1] + b2v[t].y, 0.f) * w3v[t].y;
                p += fmaxf(acc2[t][nt][2] + b2v[t].z, 0.f) * w3v[t].z;
                p += fmaxf(acc2[t][nt][3] + b2v[t].w, 0.f) * w3v[t].w;
            }
            p += __shfl_xor(p, 16);
            p += __shfl_xor(p, 32);
            if (quad == 0)
                atomicAdd(&out_lds[nt * 16 + lm], p);
        }
    }
    __syncthreads();

    if (tid < EPB) {
        int e = e0 + tid;
        if (e < N_EDGES) out[e] = out_lds[tid] + b3[0];
    }
}

extern "C" void kernel_launch(void* const* d_in, const int* in_sizes, int n_in,
                              void* d_out, int out_size, void* d_ws, size_t ws_size,
                              hipStream_t stream)
{
    const float* x          = (const float*)d_in[0];
    const int*   edge_index = (const int*)d_in[1];
    const float* edge_attr  = (const float*)d_in[2];
    const float* Wn = (const float*)d_in[3];
    const float* bn = (const float*)d_in[4];
    const float* We = (const float*)d_in[5];
    const float* be = (const float*)d_in[6];
    const float* W1 = (const float*)d_in[7];
    const float* b1 = (const float*)d_in[8];
    const float* W2 = (const float*)d_in[9];
    const float* b2 = (const float*)d_in[10];
    const float* W3 = (const float*)d_in[11];
    const float* b3 = (const float*)d_in[12];
    float* out = (float*)d_out;

    char* ws = (char*)d_ws;
    unsigned short* node_f = (unsigned short*)ws;                    // 12,800,000 B
    unsigned short* Wnp = (unsigned short*)(ws + 12800000);          // 32,768 B
    unsigned short* Wep = (unsigned short*)(ws + 12832768);          // 16,384 B
    unsigned short* W1p = (unsigned short*)(ws + 12849152);          // 393,216 B
    unsigned short* W2p = (unsigned short*)(ws + 13242368);          // 262,144 B

    pack_all<<<(PACK_TOTAL + 255) / 256, 256, 0, stream>>>(Wn, We, W1, W2, Wnp, Wep, W1p, W2p);

    node_feat_kernel<<<(N_NODES + 63) / 64, 256, 0, stream>>>(x, Wnp, bn, node_f);

    fused_edge_kernel<<<(N_EDGES + EPB - 1) / EPB, 512, 0, stream>>>(
        edge_index, edge_attr, node_f, Wep, be, W1p, b1, W2p, b2, W3, b3, out);
}